// Round 1
// 378.540 us; speedup vs baseline: 1.1698x; 1.1698x over previous
//
#include <hip/hip_runtime.h>
#include <cstdint>

#define NN 100000
#define EE 1600000
#define HH 128
#define NREP 8
#define PSZ (NN / 8)                 // 12500 rows per partition
#define SS 64                        // sub-slices per partition
#define CAP 300000                   // per-partition bucket capacity (entries)
#define NBB 500                      // bucket blocks
#define BCH 3200                     // edges per bucket block (500*3200 = EE)
#define SCAN_CHUNK 512
#define NSCAN ((NN + SCAN_CHUNK - 1) / SCAN_CHUNK)   // 196

typedef unsigned long long u64;
typedef unsigned short ushort;
typedef unsigned char uchar;
typedef __attribute__((ext_vector_type(8))) short bf16x8;
typedef __attribute__((ext_vector_type(4))) float f32x4;
typedef __attribute__((ext_vector_type(2))) float f32x2;

// ---------- bf16 helpers (RNE, finite values) ----------
__device__ __forceinline__ ushort f2bf(float x) {
    union { float f; unsigned u; } v; v.f = x;
    unsigned r = v.u + 0x7fffu + ((v.u >> 16) & 1u);
    return (ushort)(r >> 16);
}
__device__ __forceinline__ float bf2f(unsigned h16) {
    union { unsigned u; float f; } v; v.u = h16 << 16; return v.f;
}

// ---------- fp8 e4m3 helpers (HW cvt) ----------
__device__ __forceinline__ uchar f2fp8(float a) {
    return (uchar)(__builtin_amdgcn_cvt_pk_fp8_f32(a, a, 0, false) & 0xff);
}
__device__ __forceinline__ void unpack8_fp8(uint2 q, float* v) {
    f32x2 a = __builtin_amdgcn_cvt_pk_f32_fp8(q.x, false);
    f32x2 b = __builtin_amdgcn_cvt_pk_f32_fp8(q.x, true);
    f32x2 c = __builtin_amdgcn_cvt_pk_f32_fp8(q.y, false);
    f32x2 d = __builtin_amdgcn_cvt_pk_f32_fp8(q.y, true);
    v[0] = a[0]; v[1] = a[1]; v[2] = b[0]; v[3] = b[1];
    v[4] = c[0]; v[5] = c[1]; v[6] = d[0]; v[7] = d[1];
}

// ---------- monotone float<->uint encoding for atomicMax on floats ----------
__device__ __forceinline__ unsigned encf(float f) {
    int b = __float_as_int(f);
    return (b >= 0) ? ((unsigned)b | 0x80000000u) : ~(unsigned)b;
}
__device__ __forceinline__ float decf(unsigned u) {
    return (u & 0x80000000u) ? __int_as_float((int)(u & 0x7fffffffu))
                             : __int_as_float((int)(~u));
}
#define ENC_NEG_INF 0x007FFFFFu  // encf(-inf)

// ---------- small init ----------
__global__ void k_init(float* __restrict__ meansum, unsigned* __restrict__ maxenc,
                       unsigned* __restrict__ lmaxenc, float* __restrict__ esum,
                       int* __restrict__ gtail) {
    int i = blockIdx.x * blockDim.x + threadIdx.x;
    if (i < NREP * HH) { meansum[i] = 0.f; maxenc[i] = ENC_NEG_INF; }
    if (i < 8) gtail[i] = 0;
    if (i == 0) { lmaxenc[0] = ENC_NEG_INF; esum[0] = 0.f; }
}

// ---------- pre-transpose weights to bf16 Wt[n][k] ----------
__global__ void k_prep(const float* __restrict__ w0, const float* __restrict__ w1,
                       const float* __restrict__ w2, ushort* __restrict__ wt) {
    int idx = blockIdx.x * blockDim.x + threadIdx.x;
    if (idx >= 3 * HH * HH) return;
    int mat = idx >> 14;
    int e = idx & 16383;
    int n = e >> 7, k = e & 127;
    const float* src = (mat == 0) ? w0 : (mat == 1) ? w1 : w2;
    wt[idx] = f2bf(src[k * HH + n]);
}

// ---------- bucket: split edges into 8 partition-major packed streams ----------
// entry: (rlocal << 32) | (col << 15) | q15
__global__ __launch_bounds__(256) void k_bucket(const int* __restrict__ rows,
                                                const int* __restrict__ cols,
                                                const float* __restrict__ ea,
                                                int* __restrict__ gtail,
                                                u64* __restrict__ ebuck) {
    __shared__ u64 buf[8][1024];   // 64 KB
    __shared__ int cnt8[8];
    __shared__ int rsv[8];
    int t = threadIdx.x;
    if (t < 8) cnt8[t] = 0;
    __syncthreads();
    int e0 = blockIdx.x * BCH;
    int e1 = e0 + BCH;
    for (int ebase = e0; ebase < e1; ebase += 1024) {
        int e = ebase + t * 4;
        if (e < e1) {
            int4 r4 = *(const int4*)(rows + e);
            int4 c4 = *(const int4*)(cols + e);
            float4 a4 = *(const float4*)(ea + e);
            int rr[4] = {r4.x, r4.y, r4.z, r4.w};
            int cc[4] = {c4.x, c4.y, c4.z, c4.w};
            float aa[4] = {a4.x, a4.y, a4.z, a4.w};
#pragma unroll
            for (int j = 0; j < 4; ++j) {
                int p = rr[j] / PSZ;
                int rl = rr[j] - p * PSZ;
                unsigned q = (unsigned)(aa[j] * 32767.0f + 0.5f);
                u64 en = ((u64)rl << 32) | (u64)(((unsigned)cc[j] << 15) | q);
                int idx = atomicAdd(&cnt8[p], 1);
                buf[p][idx] = en;
            }
        }
        __syncthreads();
        if (t < 8) rsv[t] = atomicAdd(&gtail[t], cnt8[t]);
        __syncthreads();
#pragma unroll
        for (int p = 0; p < 8; ++p) {
            int nn = cnt8[p], oo = rsv[p];
            u64* dst = ebuck + (size_t)p * CAP + oo;
            for (int j = t; j < nn; j += 256) dst[j] = buf[p][j];
        }
        __syncthreads();
        if (t < 8) cnt8[t] = 0;
        __syncthreads();
    }
}

// ---------- count: per-(partition,sub-slice) LDS u16x2 histogram ----------
__global__ __launch_bounds__(256) void k_cnt2(const u64* __restrict__ ebuck,
                                              const int* __restrict__ gtail,
                                              int* __restrict__ cnt) {
    __shared__ unsigned h32[PSZ / 2];   // 25 KB
    int b = blockIdx.x;
    int s = b >> 3, p = b & 7;
    for (int j = threadIdx.x; j < PSZ / 2; j += 256) h32[j] = 0;
    __syncthreads();
    int pc = gtail[p];
    int len = (pc + SS - 1) / SS;
    int lo = s * len, hi = min(lo + len, pc);
    const u64* src = ebuck + (size_t)p * CAP;
    for (int i = lo + threadIdx.x; i < hi; i += 256) {
        int rl = (int)(src[i] >> 32);
        atomicAdd(&h32[rl >> 1], (rl & 1) ? 0x10000u : 1u);
    }
    __syncthreads();
    int* dst = cnt + (size_t)(p * SS + s) * PSZ;
    for (int j = threadIdx.x; j < PSZ / 2; j += 256) {
        unsigned v = h32[j];
        ((int2*)dst)[j] = make_int2((int)(v & 0xffffu), (int)(v >> 16));
    }
}

// ---------- count[r] = sum over sub-slices ----------
__global__ void k_rowsum(const int* __restrict__ cnt, int* __restrict__ count) {
    int r = blockIdx.x * blockDim.x + threadIdx.x;
    if (r >= NN) return;
    int p = r / PSZ, rl = r - p * PSZ;
    int s = 0;
#pragma unroll 8
    for (int c = 0; c < SS; ++c) s += cnt[(size_t)(p * SS + c) * PSZ + rl];
    count[r] = s;
}

// ---------- exclusive scan of count -> base ----------
__global__ void k_scan1(const int* __restrict__ cnt, int* __restrict__ out,
                        int* __restrict__ bsum) {
    int b = blockIdx.x, t = threadIdx.x;
    int i0 = b * SCAN_CHUNK + t * 2;
    int c0 = (i0 < NN) ? cnt[i0] : 0;
    int c1 = (i0 + 1 < NN) ? cnt[i0 + 1] : 0;
    int s = c0 + c1;
    int lane = t & 63, w = t >> 6;
    int v = s;
#pragma unroll
    for (int off = 1; off < 64; off <<= 1) {
        int u = __shfl_up(v, off, 64);
        if (lane >= off) v += u;
    }
    __shared__ int wsum[4];
    if (lane == 63) wsum[w] = v;
    __syncthreads();
    int wadd = 0;
    for (int j = 0; j < w; ++j) wadd += wsum[j];
    int incl = v + wadd;
    int excl = incl - s;
    if (i0 < NN) out[i0] = excl;
    if (i0 + 1 < NN) out[i0 + 1] = excl + c0;
    if (t == 255) bsum[b] = incl;
}

__global__ void k_scan2(int* __restrict__ bsum) {
    __shared__ int tmp[256];
    int t = threadIdx.x;
    int v = (t < NSCAN) ? bsum[t] : 0;
    tmp[t] = v;
    __syncthreads();
    for (int off = 1; off < 256; off <<= 1) {
        int u = (t >= off) ? tmp[t - off] : 0;
        __syncthreads();
        tmp[t] += u;
        __syncthreads();
    }
    if (t < NSCAN) bsum[t] = tmp[t] - v;  // exclusive
}

__global__ void k_scan3(int* __restrict__ out, const int* __restrict__ bsum) {
    int i = blockIdx.x * blockDim.x + threadIdx.x;
    if (i < NN) out[i] += bsum[i / SCAN_CHUNK];
    if (i == 0) out[NN] = EE;   // sentinel
}

// ---------- per-(partition,sub-slice,row) fill starts ----------
__global__ void k_makeptr(const int* __restrict__ cnt, const int* __restrict__ base,
                          int* __restrict__ fillptr) {
    int r = blockIdx.x * blockDim.x + threadIdx.x;
    if (r >= NN) return;
    int p = r / PSZ, rl = r - p * PSZ;
    int acc = base[r];
#pragma unroll 8
    for (int c = 0; c < SS; ++c) {
        fillptr[(size_t)(p * SS + c) * PSZ + rl] = acc;
        acc += cnt[(size_t)(p * SS + c) * PSZ + rl];
    }
}

// ---------- fill CSR from bucketed streams; LDS slot counters; XCD-local writes ----------
__global__ __launch_bounds__(256) void k_fill2(const u64* __restrict__ ebuck,
                                               const int* __restrict__ gtail,
                                               const int* __restrict__ fillptr,
                                               unsigned* __restrict__ csre) {
    __shared__ int nxt[PSZ];   // 50 KB
    int b = blockIdx.x;
    int s = b >> 3, p = b & 7;
    const int* fsrc = fillptr + (size_t)(p * SS + s) * PSZ;
    for (int j = threadIdx.x; j < PSZ; j += 256) nxt[j] = fsrc[j];
    __syncthreads();
    int pc = gtail[p];
    int len = (pc + SS - 1) / SS;
    int lo = s * len, hi = min(lo + len, pc);
    const u64* src = ebuck + (size_t)p * CAP;
    for (int i = lo + threadIdx.x; i < hi; i += 256) {
        u64 en = src[i];
        int rl = (int)(en >> 32);
        int slot = atomicAdd(&nxt[rl], 1);
        csre[slot] = (unsigned)(en & 0xffffffffu);
    }
}

// ---------- deg from csre segment sums -> dis ----------
__global__ void k_degsum(const unsigned* __restrict__ csre, const int* __restrict__ base,
                         float* __restrict__ dis) {
    int r = blockIdx.x * blockDim.x + threadIdx.x;
    if (r >= NN) return;
    int lo = base[r], hi = base[r + 1];
    float s = 0.f;
    for (int e = lo; e < hi; ++e) s += (float)(csre[e] & 0x7fffu);
    dis[r] = rsqrtf(1.0f + s * (1.0f / 32767.0f));
}

// ---------- gather: wave per node, 4 groups x 16 lanes; fp8 rows in, bf16 out ----------
__global__ __launch_bounds__(256) void k_gather(const uchar* __restrict__ hW,
                                                const unsigned* __restrict__ csre,
                                                const int* __restrict__ base,
                                                const float* __restrict__ dis,
                                                const float* __restrict__ bias,
                                                ushort* __restrict__ agg) {
    int node = (blockIdx.x * 256 + threadIdx.x) >> 6;
    if (node >= NN) return;
    int lane = threadIdx.x & 63;
    int g = lane >> 4, l = lane & 15;
    int f = l * 8;                     // byte offset within 128B row
    int lo = base[node], hi = base[node + 1];
    float disn = dis[node];
    float wk = disn * (1.0f / 32767.0f);
    const unsigned SELF = (unsigned)node << 15;  // weight bits = 0
    float acc[8];
#pragma unroll
    for (int j = 0; j < 8; ++j) acc[j] = 0.f;
    if (g == 0) {  // self-loop
        uint2 q = *(const uint2*)(hW + (size_t)node * HH + f);
        float v[8]; unpack8_fp8(q, v);
#pragma unroll
        for (int j = 0; j < 8; ++j) acc[j] = disn * v[j];
    }
    for (int eb = lo + g; eb < hi; eb += 16) {
        unsigned pp[4];
#pragma unroll
        for (int j = 0; j < 4; ++j) {
            int e = eb + j * 4;
            pp[j] = (e < hi) ? csre[e] : SELF;
        }
        uint2 qq[4];
#pragma unroll
        for (int j = 0; j < 4; ++j)
            qq[j] = *(const uint2*)(hW + (size_t)(pp[j] >> 15) * HH + f);
#pragma unroll
        for (int j = 0; j < 4; ++j) {
            float w = (float)(pp[j] & 0x7fffu) * wk;
            float v[8]; unpack8_fp8(qq[j], v);
#pragma unroll
            for (int k = 0; k < 8; ++k) acc[k] += w * v[k];
        }
    }
#pragma unroll
    for (int j = 0; j < 8; ++j) {
        acc[j] += __shfl_xor(acc[j], 16, 64);
        acc[j] += __shfl_xor(acc[j], 32, 64);
    }
    if (g == 0) {
        float4 b0 = *(const float4*)(bias + f);
        float4 b1 = *(const float4*)(bias + f + 4);
        ushort o[8];
        o[0] = f2bf(acc[0] + b0.x); o[1] = f2bf(acc[1] + b0.y);
        o[2] = f2bf(acc[2] + b0.z); o[3] = f2bf(acc[3] + b0.w);
        o[4] = f2bf(acc[4] + b1.x); o[5] = f2bf(acc[5] + b1.y);
        o[6] = f2bf(acc[6] + b1.z); o[7] = f2bf(acc[7] + b1.w);
        *(uint4*)(agg + (size_t)node * HH + f) = *(uint4*)o;
    }
}

// ---------- MFMA GEMM: 64x128 tile, K=128, bf16 inputs, fp32 acc ----------
// B (Wt) is staged once per block into LDS (swizzled) — the per-MFMA global
// B-loads were the latency bottleneck (48-VGPR kernel can't pipeline them).
// MODE 0: A fp32 (x), no relu    -> C_fp8 = fp8(dis*(A@W))
// MODE 1: A bf16, relu           -> C_fp8 = fp8(dis*(relu(A)@W))
// MODE 2: A bf16, relu; heads: logits + mean/masked-max
template <int MODE>
__global__ __launch_bounds__(256) void k_mfma(const void* __restrict__ Ain,
                                              const ushort* __restrict__ Wt,
                                              uchar* __restrict__ C,
                                              const float* __restrict__ dis,
                                              const float* __restrict__ b1,
                                              const float* __restrict__ w2v,
                                              const float* __restrict__ b2,
                                              const int* __restrict__ ready,
                                              float* __restrict__ logits,
                                              float* __restrict__ meansum,
                                              unsigned* __restrict__ maxenc,
                                              unsigned* __restrict__ lmaxenc, int n) {
    __shared__ ushort As[64 * HH];    // 16 KB, swizzled: elem(m,k) at m*128 + ((k>>3)^(m&15))*8 + (k&7)
    __shared__ ushort Ws[128 * HH];   // 32 KB, same swizzle: elem(nn,k) at nn*128 + ((k>>3)^(nn&15))*8 + (k&7)
    __shared__ int rdy[64];
    __shared__ unsigned slmax;
    const int t = threadIdx.x;
    const int rb = blockIdx.x * 64;
    if (MODE == 2) {
        if (t < 64) rdy[t] = (rb + t < n) ? ready[rb + t] : 0;
        if (t == 0) slmax = ENC_NEG_INF;
    }
    // stage Wt tile (bf16, swizzled) — 128 rows x 16 chunks, 8 chunks/thread
#pragma unroll
    for (int i = 0; i < 8; ++i) {
        int nr = i * 16 + (t >> 4);
        int gc = t & 15;
        uint4 q = *(const uint4*)(Wt + (size_t)nr * HH + gc * 8);
        *(uint4*)(Ws + nr * HH + ((gc ^ (nr & 15)) * 8)) = q;
    }
    // stage A tile (bf16, swizzled)
#pragma unroll
    for (int i = 0; i < 4; ++i) {
        int m = i * 16 + (t >> 4);
        int k = (t & 15) * 8;
        ushort pk[8];
        if (MODE == 0) {
            const float* Af = (const float*)Ain;
            float4 v0 = make_float4(0.f, 0.f, 0.f, 0.f), v1 = v0;
            if (rb + m < n) {
                const float* src = Af + (size_t)(rb + m) * HH + k;
                v0 = *(const float4*)src;
                v1 = *(const float4*)(src + 4);
            }
            pk[0] = f2bf(v0.x); pk[1] = f2bf(v0.y); pk[2] = f2bf(v0.z); pk[3] = f2bf(v0.w);
            pk[4] = f2bf(v1.x); pk[5] = f2bf(v1.y); pk[6] = f2bf(v1.z); pk[7] = f2bf(v1.w);
        } else {
            const ushort* Au = (const ushort*)Ain;
            uint4 q = make_uint4(0, 0, 0, 0);
            if (rb + m < n) q = *(const uint4*)(Au + (size_t)(rb + m) * HH + k);
            *(uint4*)pk = q;
#pragma unroll
            for (int j = 0; j < 8; ++j) pk[j] = (pk[j] & 0x8000) ? (ushort)0 : pk[j];  // bf16 relu
        }
        int gsw = (t & 15) ^ (m & 15);
        *(uint4*)(As + m * HH + gsw * 8) = *(uint4*)pk;
    }
    __syncthreads();

    const int wave = t >> 6, lane = t & 63;
    const int cl = lane & 15;       // column-within-tile / A row
    const int kq = lane >> 4;       // k quad
    const int m0 = wave * 16;

    f32x4 acc[8];
#pragma unroll
    for (int c = 0; c < 8; ++c) acc[c] = (f32x4){0.f, 0.f, 0.f, 0.f};

    const int am = m0 + cl;
#pragma unroll
    for (int kk = 0; kk < 4; ++kk) {
        int g = kk * 4 + kq;
        bf16x8 a = *(const bf16x8*)(As + am * HH + ((g ^ cl) * 8));
#pragma unroll
        for (int c = 0; c < 8; ++c) {
            // B row nn = c*16+cl (nn&15 == cl), chunk g → swizzled slot g^cl
            bf16x8 b = *(const bf16x8*)(Ws + (c * 16 + cl) * HH + ((g ^ cl) * 8));
            acc[c] = __builtin_amdgcn_mfma_f32_16x16x32_bf16(a, b, acc[c], 0, 0, 0);
        }
    }

    if (MODE < 2) {
        // store C fp8 pre-scaled by dis[row]: D row = m0 + kq*4 + r, col = c*16 + cl
#pragma unroll
        for (int r = 0; r < 4; ++r) {
            int row = rb + m0 + kq * 4 + r;
            if (row < n) {
                float dsc = dis[row];
#pragma unroll
                for (int c = 0; c < 8; ++c)
                    C[(size_t)row * HH + c * 16 + cl] = f2fp8(acc[c][r] * dsc);
            }
        }
    } else {
        // heads epilogue
        float b1c[8], w2c[8];
#pragma unroll
        for (int c = 0; c < 8; ++c) { b1c[c] = b1[c * 16 + cl]; w2c[c] = w2v[c * 16 + cl]; }
        const float b2s = b2[0];
        unsigned mylmax = ENC_NEG_INF;
#pragma unroll
        for (int r = 0; r < 4; ++r) {
            float s = 0.f;
#pragma unroll
            for (int c = 0; c < 8; ++c)
                s += fmaxf(acc[c][r] + b1c[c], 0.f) * w2c[c];
            s += __shfl_xor(s, 1, 64);
            s += __shfl_xor(s, 2, 64);
            s += __shfl_xor(s, 4, 64);
            s += __shfl_xor(s, 8, 64);
            if (cl == 0) {
                int rloc = m0 + kq * 4 + r;
                int row = rb + rloc;
                if (row < n) {
                    float lg = s + b2s;
                    logits[row] = lg;
                    if (rdy[rloc] > 0) {
                        unsigned e = encf(lg);
                        if (e > mylmax) mylmax = e;
                    }
                }
            }
        }
        if (cl == 0 && mylmax != ENC_NEG_INF) atomicMax(&slmax, mylmax);

        // mean / masked-max of h = relu(A) (bf16 tile), per feature
        int lim = min(64, n - rb);
        if (t < HH) {
            int f = t, gf = f >> 3, fo = f & 7;
            float sum = 0.f, mx = -3.4e38f;
            for (int m = 0; m < lim; ++m) {
                float v = bf2f(As[m * HH + ((gf ^ (m & 15)) * 8) + fo]);
                sum += v;
                if (rdy[m] > 0) mx = fmaxf(mx, v);
            }
            int rep = blockIdx.x & (NREP - 1);
            atomicAdd(&meansum[rep * HH + f], sum);
            if (mx > -3.0e38f) atomicMax(&maxenc[rep * HH + f], encf(mx));
        }
        __syncthreads();
        if (t == 0 && slmax != ENC_NEG_INF) atomicMax(lmaxenc, slmax);
    }
}

// ---------- small finalize: fc, pass-MLP, v, global max M ----------
__global__ void k_fin1(const float* __restrict__ meansum, const unsigned* __restrict__ maxenc,
                       const unsigned* __restrict__ lmaxenc,
                       const float* __restrict__ val_w, const float* __restrict__ val_b,
                       const float* __restrict__ pe, const float* __restrict__ cl_w,
                       const float* __restrict__ cl_b, const float* __restrict__ pw1,
                       const float* __restrict__ pb1, const float* __restrict__ pw2,
                       const float* __restrict__ pb2, float* __restrict__ scal,
                       float* __restrict__ d_out) {
    __shared__ float xp[144];
    __shared__ float msum[HH];
    __shared__ float zp[HH];
    int t = threadIdx.x;
    if (t < HH) {
        float s = 0.f;
        unsigned mx = ENC_NEG_INF;
#pragma unroll
        for (int r = 0; r < NREP; ++r) {
            s += meansum[r * HH + t];
            unsigned e = maxenc[r * HH + t];
            if (e > mx) mx = e;
        }
        msum[t] = s;
        xp[t] = decf(mx);
    } else if (t < 144) {
        int c = t - HH;
        float s = cl_b[c];
        for (int k = 0; k < 30; ++k) s += pe[k] * cl_w[k * 16 + c];
        xp[t] = s;
    }
    __syncthreads();
    if (t < HH) {
        float s = pb1[t];
        for (int k = 0; k < 144; ++k) s += xp[k] * pw1[k * HH + t];
        zp[t] = fmaxf(s, 0.f);
    }
    __syncthreads();
    if (t < 64) {
        float s1 = zp[t] * pw2[t] + zp[t + 64] * pw2[t + 64];
        float s2 = msum[t] * val_w[t] + msum[t + 64] * val_w[t + 64];
#pragma unroll
        for (int off = 32; off > 0; off >>= 1) {
            s1 += __shfl_xor(s1, off, 64);
            s2 += __shfl_xor(s2, off, 64);
        }
        if (t == 0) {
            float xpass = s1 + pb2[0];
            float v = s2 * (1.0f / NN) + val_b[0];
            float M = fmaxf(decf(lmaxenc[0]), xpass);
            scal[0] = M;
            scal[1] = expf(xpass - M);
            d_out[NN + 1] = v;
        }
    }
}

// ---------- exp pass: unnormalized probs + sum ----------
__global__ __launch_bounds__(256) void k_exp(const float* __restrict__ logits,
                                             const int* __restrict__ ready,
                                             const float* __restrict__ scal,
                                             float* __restrict__ d_out,
                                             float* __restrict__ esum) {
    __shared__ float warr[4];
    int t = threadIdx.x;
    int i = blockIdx.x * 256 + t;
    float M = scal[0];
    float p = 0.f;
    if (i < NN) {
        if (ready[i] > 0) p = expf(logits[i] - M);
        d_out[i] = p;
    }
    float s = p;
#pragma unroll
    for (int off = 32; off > 0; off >>= 1) s += __shfl_xor(s, off, 64);
    if ((t & 63) == 0) warr[t >> 6] = s;
    __syncthreads();
    if (t == 0) atomicAdd(esum, warr[0] + warr[1] + warr[2] + warr[3]);
}

// ---------- normalize ----------
__global__ void k_scale(const float* __restrict__ esum, const float* __restrict__ scal,
                        float* __restrict__ d_out) {
    int i = blockIdx.x * blockDim.x + threadIdx.x;
    float inv = 1.0f / (esum[0] + scal[1]);
    if (i < NN) d_out[i] *= inv;
    else if (i == NN) d_out[NN] = scal[1] * inv;
}

extern "C" void kernel_launch(void* const* d_in, const int* in_sizes, int n_in,
                              void* d_out, int out_size, void* d_ws, size_t ws_size,
                              hipStream_t stream) {
    const float* x      = (const float*)d_in[0];
    const int*   edges  = (const int*)d_in[1];
    const float* eattr  = (const float*)d_in[2];
    const int*   ready  = (const int*)d_in[3];
    const float* pe     = (const float*)d_in[4];
    const float* gcn_w  = (const float*)d_in[5];
    const float* gcn_b  = (const float*)d_in[6];
    const float* mlp_w1 = (const float*)d_in[7];
    const float* mlp_b1 = (const float*)d_in[8];
    const float* mlp_w2 = (const float*)d_in[9];
    const float* mlp_b2 = (const float*)d_in[10];
    const float* val_w  = (const float*)d_in[11];
    const float* val_b  = (const float*)d_in[12];
    const float* cl_w   = (const float*)d_in[13];
    const float* cl_b   = (const float*)d_in[14];
    const float* pw1    = (const float*)d_in[15];
    const float* pb1    = (const float*)d_in[16];
    const float* pw2    = (const float*)d_in[17];
    const float* pb2    = (const float*)d_in[18];

    const int* rows = edges;
    const int* cols = edges + EE;

    // workspace carving (256B-aligned slices), ~92 MB
    char* P = (char*)d_ws;
    size_t off = 0;
    auto carve = [&](size_t bytes) {
        off = (off + 255) & ~(size_t)255;
        void* p = P + off;
        off += bytes;
        return p;
    };
    float* dis     = (float*)carve(NN * 4);
    float* logits  = (float*)carve(NN * 4);
    int*   count   = (int*)carve(NN * 4);
    int*   base    = (int*)carve((NN + 1) * 4);
    int*   bsum    = (int*)carve(256 * 4);
    ushort* bufB   = (ushort*)carve((size_t)NN * HH * 2);   // bf16 (gather out / gemm in)
    uchar* bufH    = (uchar*)carve((size_t)NN * HH);        // fp8 (gemm out / gather in)
    unsigned* csre = (unsigned*)carve((size_t)EE * 4);      // packed (col<<15|ea15)
    u64*   ebuck   = (u64*)carve((size_t)8 * CAP * 8);      // partition-major streams
    int*   fillptr = (int*)carve((size_t)8 * SS * PSZ * 4);
    float* meansum = (float*)carve(NREP * HH * 4);
    unsigned* maxenc = (unsigned*)carve(NREP * HH * 4);
    unsigned* lmaxenc = (unsigned*)carve(4);
    float* esum    = (float*)carve(4);
    float* scal    = (float*)carve(8);
    int*   gtail   = (int*)carve(8 * 4);
    ushort* wt     = (ushort*)carve(3 * HH * HH * 2);

    // alias (lifetime-disjoint): cnt (8*SS*PSZ int = 25.6MB, used k_cnt2..k_makeptr)
    // aliases bufB (25.6MB, first written by k_gather after fill2)
    int* cnt = (int*)bufB;

    float* out = (float*)d_out;

    const int nb = (NN + 255) / 256;
    const int gb = (NN + 63) / 64;
    const int ab = (NN * 64 + 255) / 256;   // gather: wave per node
    const int pb = 8 * SS;                  // cnt2/fill2 blocks

    k_init<<<(NREP * HH + 255) / 256, 256, 0, stream>>>(meansum, maxenc, lmaxenc, esum, gtail);
    k_prep<<<(3 * HH * HH + 255) / 256, 256, 0, stream>>>(gcn_w, gcn_w + HH * HH, mlp_w1, wt);

    // CSR build: bucket -> count -> scan -> fill (all coalesced, single-owner lines)
    k_bucket<<<NBB, 256, 0, stream>>>(rows, cols, eattr, gtail, ebuck);
    k_cnt2<<<pb, 256, 0, stream>>>(ebuck, gtail, cnt);
    k_rowsum<<<nb, 256, 0, stream>>>(cnt, count);
    k_scan1<<<NSCAN, 256, 0, stream>>>(count, base, bsum);
    k_scan2<<<1, 256, 0, stream>>>(bsum);
    k_scan3<<<nb, 256, 0, stream>>>(base, bsum);
    k_makeptr<<<nb, 256, 0, stream>>>(cnt, base, fillptr);
    k_fill2<<<pb, 256, 0, stream>>>(ebuck, gtail, fillptr, csre);
    k_degsum<<<nb, 256, 0, stream>>>(csre, base, dis);

    // layer 0
    k_mfma<0><<<gb, 256, 0, stream>>>(x, wt, bufH, dis, nullptr, nullptr, nullptr, nullptr,
                                      nullptr, nullptr, nullptr, nullptr, NN);
    k_gather<<<ab, 256, 0, stream>>>(bufH, csre, base, dis, gcn_b, bufB);

    // layer 1 (bf16 relu on staging)
    k_mfma<1><<<gb, 256, 0, stream>>>(bufB, wt + HH * HH, bufH, dis, nullptr, nullptr, nullptr,
                                      nullptr, nullptr, nullptr, nullptr, nullptr, NN);
    k_gather<<<ab, 256, 0, stream>>>(bufH, csre, base, dis, gcn_b + HH, bufB);

    // heads
    k_mfma<2><<<gb, 256, 0, stream>>>(bufB, wt + 2 * HH * HH, nullptr, nullptr, mlp_b1, mlp_w2,
                                      mlp_b2, ready, logits, meansum, maxenc, lmaxenc, NN);
    k_fin1<<<1, 256, 0, stream>>>(meansum, maxenc, lmaxenc, val_w, val_b, pe, cl_w, cl_b,
                                  pw1, pb1, pw2, pb2, scal, out);
    k_exp<<<nb, 256, 0, stream>>>(logits, ready, scal, out, esum);
    k_scale<<<(NN + 1 + 255) / 256, 256, 0, stream>>>(esum, scal, out);
}

// Round 2
// 361.539 us; speedup vs baseline: 1.2248x; 1.0470x over previous
//
#include <hip/hip_runtime.h>
#include <cstdint>

#define NN 100000
#define EE 1600000
#define HH 128
#define NREP 8
#define PSZ (NN / 8)                 // 12500 rows per partition
#define SS 64                        // sub-slices per partition
#define CAP 300000                   // per-partition bucket capacity (entries)
#define NBB 500                      // bucket blocks
#define BCH 3200                     // edges per bucket block (500*3200 = EE)
#define SCAN_CHUNK 512
#define NSCAN ((NN + SCAN_CHUNK - 1) / SCAN_CHUNK)   // 196

typedef unsigned long long u64;
typedef unsigned short ushort;
typedef unsigned char uchar;
typedef __attribute__((ext_vector_type(8))) short bf16x8;
typedef __attribute__((ext_vector_type(4))) float f32x4;
typedef __attribute__((ext_vector_type(2))) float f32x2;

// ---------- bf16 helpers (RNE, finite values) ----------
__device__ __forceinline__ ushort f2bf(float x) {
    union { float f; unsigned u; } v; v.f = x;
    unsigned r = v.u + 0x7fffu + ((v.u >> 16) & 1u);
    return (ushort)(r >> 16);
}
__device__ __forceinline__ float bf2f(unsigned h16) {
    union { unsigned u; float f; } v; v.u = h16 << 16; return v.f;
}

// ---------- fp8 e4m3 helpers (HW cvt) ----------
__device__ __forceinline__ uchar f2fp8(float a) {
    return (uchar)(__builtin_amdgcn_cvt_pk_fp8_f32(a, a, 0, false) & 0xff);
}
__device__ __forceinline__ void unpack8_fp8(uint2 q, float* v) {
    f32x2 a = __builtin_amdgcn_cvt_pk_f32_fp8(q.x, false);
    f32x2 b = __builtin_amdgcn_cvt_pk_f32_fp8(q.x, true);
    f32x2 c = __builtin_amdgcn_cvt_pk_f32_fp8(q.y, false);
    f32x2 d = __builtin_amdgcn_cvt_pk_f32_fp8(q.y, true);
    v[0] = a[0]; v[1] = a[1]; v[2] = b[0]; v[3] = b[1];
    v[4] = c[0]; v[5] = c[1]; v[6] = d[0]; v[7] = d[1];
}

// ---------- monotone float<->uint encoding for atomicMax on floats ----------
__device__ __forceinline__ unsigned encf(float f) {
    int b = __float_as_int(f);
    return (b >= 0) ? ((unsigned)b | 0x80000000u) : ~(unsigned)b;
}
__device__ __forceinline__ float decf(unsigned u) {
    return (u & 0x80000000u) ? __int_as_float((int)(u & 0x7fffffffu))
                             : __int_as_float((int)(~u));
}
#define ENC_NEG_INF 0x007FFFFFu  // encf(-inf)

// ---------- small init ----------
__global__ void k_init(float* __restrict__ meansum, unsigned* __restrict__ maxenc,
                       unsigned* __restrict__ lmaxenc, float* __restrict__ esum,
                       int* __restrict__ gtail) {
    int i = blockIdx.x * blockDim.x + threadIdx.x;
    if (i < NREP * HH) { meansum[i] = 0.f; maxenc[i] = ENC_NEG_INF; }
    if (i < 8) gtail[i] = 0;
    if (i == 0) { lmaxenc[0] = ENC_NEG_INF; esum[0] = 0.f; }
}

// ---------- pre-transpose weights to bf16 Wt[n][k] ----------
__global__ void k_prep(const float* __restrict__ w0, const float* __restrict__ w1,
                       const float* __restrict__ w2, ushort* __restrict__ wt) {
    int idx = blockIdx.x * blockDim.x + threadIdx.x;
    if (idx >= 3 * HH * HH) return;
    int mat = idx >> 14;
    int e = idx & 16383;
    int n = e >> 7, k = e & 127;
    const float* src = (mat == 0) ? w0 : (mat == 1) ? w1 : w2;
    wt[idx] = f2bf(src[k * HH + n]);
}

// ---------- bucket: split edges into 8 partition-major packed streams ----------
// entry: (rlocal << 32) | (col << 15) | q15
__global__ __launch_bounds__(256) void k_bucket(const int* __restrict__ rows,
                                                const int* __restrict__ cols,
                                                const float* __restrict__ ea,
                                                int* __restrict__ gtail,
                                                u64* __restrict__ ebuck) {
    __shared__ u64 buf[8][1024];   // 64 KB
    __shared__ int cnt8[8];
    __shared__ int rsv[8];
    int t = threadIdx.x;
    if (t < 8) cnt8[t] = 0;
    __syncthreads();
    int e0 = blockIdx.x * BCH;
    int e1 = e0 + BCH;
    for (int ebase = e0; ebase < e1; ebase += 1024) {
        int e = ebase + t * 4;
        if (e < e1) {
            int4 r4 = *(const int4*)(rows + e);
            int4 c4 = *(const int4*)(cols + e);
            float4 a4 = *(const float4*)(ea + e);
            int rr[4] = {r4.x, r4.y, r4.z, r4.w};
            int cc[4] = {c4.x, c4.y, c4.z, c4.w};
            float aa[4] = {a4.x, a4.y, a4.z, a4.w};
#pragma unroll
            for (int j = 0; j < 4; ++j) {
                int p = rr[j] / PSZ;
                int rl = rr[j] - p * PSZ;
                unsigned q = (unsigned)(aa[j] * 32767.0f + 0.5f);
                u64 en = ((u64)rl << 32) | (u64)(((unsigned)cc[j] << 15) | q);
                int idx = atomicAdd(&cnt8[p], 1);
                buf[p][idx] = en;
            }
        }
        __syncthreads();
        if (t < 8) rsv[t] = atomicAdd(&gtail[t], cnt8[t]);
        __syncthreads();
#pragma unroll
        for (int p = 0; p < 8; ++p) {
            int nn = cnt8[p], oo = rsv[p];
            u64* dst = ebuck + (size_t)p * CAP + oo;
            for (int j = t; j < nn; j += 256) dst[j] = buf[p][j];
        }
        __syncthreads();
        if (t < 8) cnt8[t] = 0;
        __syncthreads();
    }
}

// ---------- count: per-(partition,sub-slice) LDS u16x2 histogram ----------
__global__ __launch_bounds__(256) void k_cnt2(const u64* __restrict__ ebuck,
                                              const int* __restrict__ gtail,
                                              int* __restrict__ cnt) {
    __shared__ unsigned h32[PSZ / 2];   // 25 KB
    int b = blockIdx.x;
    int s = b >> 3, p = b & 7;
    for (int j = threadIdx.x; j < PSZ / 2; j += 256) h32[j] = 0;
    __syncthreads();
    int pc = gtail[p];
    int len = (pc + SS - 1) / SS;
    int lo = s * len, hi = min(lo + len, pc);
    const u64* src = ebuck + (size_t)p * CAP;
    for (int i = lo + threadIdx.x; i < hi; i += 256) {
        int rl = (int)(src[i] >> 32);
        atomicAdd(&h32[rl >> 1], (rl & 1) ? 0x10000u : 1u);
    }
    __syncthreads();
    int* dst = cnt + (size_t)(p * SS + s) * PSZ;
    for (int j = threadIdx.x; j < PSZ / 2; j += 256) {
        unsigned v = h32[j];
        ((int2*)dst)[j] = make_int2((int)(v & 0xffffu), (int)(v >> 16));
    }
}

// ---------- count[r] = sum over sub-slices ----------
__global__ void k_rowsum(const int* __restrict__ cnt, int* __restrict__ count) {
    int r = blockIdx.x * blockDim.x + threadIdx.x;
    if (r >= NN) return;
    int p = r / PSZ, rl = r - p * PSZ;
    int s = 0;
#pragma unroll 8
    for (int c = 0; c < SS; ++c) s += cnt[(size_t)(p * SS + c) * PSZ + rl];
    count[r] = s;
}

// ---------- exclusive scan of count -> base ----------
__global__ void k_scan1(const int* __restrict__ cnt, int* __restrict__ out,
                        int* __restrict__ bsum) {
    int b = blockIdx.x, t = threadIdx.x;
    int i0 = b * SCAN_CHUNK + t * 2;
    int c0 = (i0 < NN) ? cnt[i0] : 0;
    int c1 = (i0 + 1 < NN) ? cnt[i0 + 1] : 0;
    int s = c0 + c1;
    int lane = t & 63, w = t >> 6;
    int v = s;
#pragma unroll
    for (int off = 1; off < 64; off <<= 1) {
        int u = __shfl_up(v, off, 64);
        if (lane >= off) v += u;
    }
    __shared__ int wsum[4];
    if (lane == 63) wsum[w] = v;
    __syncthreads();
    int wadd = 0;
    for (int j = 0; j < w; ++j) wadd += wsum[j];
    int incl = v + wadd;
    int excl = incl - s;
    if (i0 < NN) out[i0] = excl;
    if (i0 + 1 < NN) out[i0 + 1] = excl + c0;
    if (t == 255) bsum[b] = incl;
}

__global__ void k_scan2(int* __restrict__ bsum) {
    __shared__ int tmp[256];
    int t = threadIdx.x;
    int v = (t < NSCAN) ? bsum[t] : 0;
    tmp[t] = v;
    __syncthreads();
    for (int off = 1; off < 256; off <<= 1) {
        int u = (t >= off) ? tmp[t - off] : 0;
        __syncthreads();
        tmp[t] += u;
        __syncthreads();
    }
    if (t < NSCAN) bsum[t] = tmp[t] - v;  // exclusive
}

__global__ void k_scan3(int* __restrict__ out, const int* __restrict__ bsum) {
    int i = blockIdx.x * blockDim.x + threadIdx.x;
    if (i < NN) out[i] += bsum[i / SCAN_CHUNK];
    if (i == 0) out[NN] = EE;   // sentinel
}

// ---------- per-(partition,sub-slice,row) fill starts ----------
__global__ void k_makeptr(const int* __restrict__ cnt, const int* __restrict__ base,
                          int* __restrict__ fillptr) {
    int r = blockIdx.x * blockDim.x + threadIdx.x;
    if (r >= NN) return;
    int p = r / PSZ, rl = r - p * PSZ;
    int acc = base[r];
#pragma unroll 8
    for (int c = 0; c < SS; ++c) {
        fillptr[(size_t)(p * SS + c) * PSZ + rl] = acc;
        acc += cnt[(size_t)(p * SS + c) * PSZ + rl];
    }
}

// ---------- fill CSR from bucketed streams; LDS slot counters; XCD-local writes ----------
__global__ __launch_bounds__(256) void k_fill2(const u64* __restrict__ ebuck,
                                               const int* __restrict__ gtail,
                                               const int* __restrict__ fillptr,
                                               unsigned* __restrict__ csre) {
    __shared__ int nxt[PSZ];   // 50 KB
    int b = blockIdx.x;
    int s = b >> 3, p = b & 7;
    const int* fsrc = fillptr + (size_t)(p * SS + s) * PSZ;
    for (int j = threadIdx.x; j < PSZ; j += 256) nxt[j] = fsrc[j];
    __syncthreads();
    int pc = gtail[p];
    int len = (pc + SS - 1) / SS;
    int lo = s * len, hi = min(lo + len, pc);
    const u64* src = ebuck + (size_t)p * CAP;
    for (int i = lo + threadIdx.x; i < hi; i += 256) {
        u64 en = src[i];
        int rl = (int)(en >> 32);
        int slot = atomicAdd(&nxt[rl], 1);
        csre[slot] = (unsigned)(en & 0xffffffffu);
    }
}

// ---------- deg from csre segment sums -> dis ----------
__global__ void k_degsum(const unsigned* __restrict__ csre, const int* __restrict__ base,
                         float* __restrict__ dis) {
    int r = blockIdx.x * blockDim.x + threadIdx.x;
    if (r >= NN) return;
    int lo = base[r], hi = base[r + 1];
    float s = 0.f;
    for (int e = lo; e < hi; ++e) s += (float)(csre[e] & 0x7fffu);
    dis[r] = rsqrtf(1.0f + s * (1.0f / 32767.0f));
}

// ---------- gather: 16-lane group per node (4 nodes/wave); fp8 rows in, bf16 out ----------
// v2: was wave-per-node with 4 groups + shfl_xor combine. Avg degree ~17 meant
// 32 edge-slots/node of padded work + 16-lane-wide epilogue. Group-per-node:
// 20 slots/node, no shuffles, full-width epilogue. Same MLP (16 row loads in
// flight per wave).
__global__ __launch_bounds__(256) void k_gather(const uchar* __restrict__ hW,
                                                const unsigned* __restrict__ csre,
                                                const int* __restrict__ base,
                                                const float* __restrict__ dis,
                                                const float* __restrict__ bias,
                                                ushort* __restrict__ agg) {
    int node = blockIdx.x * 16 + (threadIdx.x >> 4);
    if (node >= NN) return;
    int l = threadIdx.x & 15;
    int f = l * 8;                     // byte offset within 128B row
    int lo = base[node], hi = base[node + 1];
    float disn = dis[node];
    float wk = disn * (1.0f / 32767.0f);
    const unsigned SELF = (unsigned)node << 15;  // weight bits = 0
    float acc[8];
    {   // self-loop (all 16 lanes of the group)
        uint2 q = *(const uint2*)(hW + (size_t)node * HH + f);
        float v[8]; unpack8_fp8(q, v);
#pragma unroll
        for (int j = 0; j < 8; ++j) acc[j] = disn * v[j];
    }
    for (int eb = lo; eb < hi; eb += 4) {
        unsigned pp[4];
#pragma unroll
        for (int j = 0; j < 4; ++j) {
            int e = eb + j;
            pp[j] = (e < hi) ? csre[e] : SELF;   // pad: weight bits 0, row L1-hot
        }
        uint2 qq[4];
#pragma unroll
        for (int j = 0; j < 4; ++j)
            qq[j] = *(const uint2*)(hW + (size_t)(pp[j] >> 15) * HH + f);
#pragma unroll
        for (int j = 0; j < 4; ++j) {
            float w = (float)(pp[j] & 0x7fffu) * wk;
            float v[8]; unpack8_fp8(qq[j], v);
#pragma unroll
            for (int k = 0; k < 8; ++k) acc[k] += w * v[k];
        }
    }
    float4 b0 = *(const float4*)(bias + f);
    float4 b1 = *(const float4*)(bias + f + 4);
    ushort o[8];
    o[0] = f2bf(acc[0] + b0.x); o[1] = f2bf(acc[1] + b0.y);
    o[2] = f2bf(acc[2] + b0.z); o[3] = f2bf(acc[3] + b0.w);
    o[4] = f2bf(acc[4] + b1.x); o[5] = f2bf(acc[5] + b1.y);
    o[6] = f2bf(acc[6] + b1.z); o[7] = f2bf(acc[7] + b1.w);
    *(uint4*)(agg + (size_t)node * HH + f) = *(uint4*)o;
}

// ---------- MFMA GEMM: 64x128 tile, K=128, bf16 inputs, fp32 acc ----------
// B (Wt) is staged once per block into LDS (swizzled) — the per-MFMA global
// B-loads were the latency bottleneck (48-VGPR kernel can't pipeline them).
// MODE 0: A fp32 (x), no relu    -> C_fp8 = fp8(dis*(A@W))
// MODE 1: A bf16, relu           -> C_fp8 = fp8(dis*(relu(A)@W))
// MODE 2: A bf16, relu; heads: logits + mean/masked-max
template <int MODE>
__global__ __launch_bounds__(256) void k_mfma(const void* __restrict__ Ain,
                                              const ushort* __restrict__ Wt,
                                              uchar* __restrict__ C,
                                              const float* __restrict__ dis,
                                              const float* __restrict__ b1,
                                              const float* __restrict__ w2v,
                                              const float* __restrict__ b2,
                                              const int* __restrict__ ready,
                                              float* __restrict__ logits,
                                              float* __restrict__ meansum,
                                              unsigned* __restrict__ maxenc,
                                              unsigned* __restrict__ lmaxenc, int n) {
    __shared__ ushort As[64 * HH];    // 16 KB, swizzled: elem(m,k) at m*128 + ((k>>3)^(m&15))*8 + (k&7)
    __shared__ ushort Ws[128 * HH];   // 32 KB, same swizzle: elem(nn,k) at nn*128 + ((k>>3)^(nn&15))*8 + (k&7)
    __shared__ int rdy[64];
    __shared__ unsigned slmax;
    const int t = threadIdx.x;
    const int rb = blockIdx.x * 64;
    if (MODE == 2) {
        if (t < 64) rdy[t] = (rb + t < n) ? ready[rb + t] : 0;
        if (t == 0) slmax = ENC_NEG_INF;
    }
    // stage Wt tile (bf16, swizzled) — 128 rows x 16 chunks, 8 chunks/thread
#pragma unroll
    for (int i = 0; i < 8; ++i) {
        int nr = i * 16 + (t >> 4);
        int gc = t & 15;
        uint4 q = *(const uint4*)(Wt + (size_t)nr * HH + gc * 8);
        *(uint4*)(Ws + nr * HH + ((gc ^ (nr & 15)) * 8)) = q;
    }
    // stage A tile (bf16, swizzled)
#pragma unroll
    for (int i = 0; i < 4; ++i) {
        int m = i * 16 + (t >> 4);
        int k = (t & 15) * 8;
        ushort pk[8];
        if (MODE == 0) {
            const float* Af = (const float*)Ain;
            float4 v0 = make_float4(0.f, 0.f, 0.f, 0.f), v1 = v0;
            if (rb + m < n) {
                const float* src = Af + (size_t)(rb + m) * HH + k;
                v0 = *(const float4*)src;
                v1 = *(const float4*)(src + 4);
            }
            pk[0] = f2bf(v0.x); pk[1] = f2bf(v0.y); pk[2] = f2bf(v0.z); pk[3] = f2bf(v0.w);
            pk[4] = f2bf(v1.x); pk[5] = f2bf(v1.y); pk[6] = f2bf(v1.z); pk[7] = f2bf(v1.w);
        } else {
            const ushort* Au = (const ushort*)Ain;
            uint4 q = make_uint4(0, 0, 0, 0);
            if (rb + m < n) q = *(const uint4*)(Au + (size_t)(rb + m) * HH + k);
            *(uint4*)pk = q;
#pragma unroll
            for (int j = 0; j < 8; ++j) pk[j] = (pk[j] & 0x8000) ? (ushort)0 : pk[j];  // bf16 relu
        }
        int gsw = (t & 15) ^ (m & 15);
        *(uint4*)(As + m * HH + gsw * 8) = *(uint4*)pk;
    }
    __syncthreads();

    const int wave = t >> 6, lane = t & 63;
    const int cl = lane & 15;       // column-within-tile / A row
    const int kq = lane >> 4;       // k quad
    const int m0 = wave * 16;

    f32x4 acc[8];
#pragma unroll
    for (int c = 0; c < 8; ++c) acc[c] = (f32x4){0.f, 0.f, 0.f, 0.f};

    const int am = m0 + cl;
#pragma unroll
    for (int kk = 0; kk < 4; ++kk) {
        int g = kk * 4 + kq;
        bf16x8 a = *(const bf16x8*)(As + am * HH + ((g ^ cl) * 8));
#pragma unroll
        for (int c = 0; c < 8; ++c) {
            // B row nn = c*16+cl (nn&15 == cl), chunk g → swizzled slot g^cl
            bf16x8 b = *(const bf16x8*)(Ws + (c * 16 + cl) * HH + ((g ^ cl) * 8));
            acc[c] = __builtin_amdgcn_mfma_f32_16x16x32_bf16(a, b, acc[c], 0, 0, 0);
        }
    }

    if (MODE < 2) {
        // store C fp8 pre-scaled by dis[row]: D row = m0 + kq*4 + r, col = c*16 + cl
#pragma unroll
        for (int r = 0; r < 4; ++r) {
            int row = rb + m0 + kq * 4 + r;
            if (row < n) {
                float dsc = dis[row];
#pragma unroll
                for (int c = 0; c < 8; ++c)
                    C[(size_t)row * HH + c * 16 + cl] = f2fp8(acc[c][r] * dsc);
            }
        }
    } else {
        // heads epilogue
        float b1c[8], w2c[8];
#pragma unroll
        for (int c = 0; c < 8; ++c) { b1c[c] = b1[c * 16 + cl]; w2c[c] = w2v[c * 16 + cl]; }
        const float b2s = b2[0];
        unsigned mylmax = ENC_NEG_INF;
#pragma unroll
        for (int r = 0; r < 4; ++r) {
            float s = 0.f;
#pragma unroll
            for (int c = 0; c < 8; ++c)
                s += fmaxf(acc[c][r] + b1c[c], 0.f) * w2c[c];
            s += __shfl_xor(s, 1, 64);
            s += __shfl_xor(s, 2, 64);
            s += __shfl_xor(s, 4, 64);
            s += __shfl_xor(s, 8, 64);
            if (cl == 0) {
                int rloc = m0 + kq * 4 + r;
                int row = rb + rloc;
                if (row < n) {
                    float lg = s + b2s;
                    logits[row] = lg;
                    if (rdy[rloc] > 0) {
                        unsigned e = encf(lg);
                        if (e > mylmax) mylmax = e;
                    }
                }
            }
        }
        if (cl == 0 && mylmax != ENC_NEG_INF) atomicMax(&slmax, mylmax);

        // mean / masked-max of h = relu(A) (bf16 tile), per feature
        int lim = min(64, n - rb);
        if (t < HH) {
            int f = t, gf = f >> 3, fo = f & 7;
            float sum = 0.f, mx = -3.4e38f;
            for (int m = 0; m < lim; ++m) {
                float v = bf2f(As[m * HH + ((gf ^ (m & 15)) * 8) + fo]);
                sum += v;
                if (rdy[m] > 0) mx = fmaxf(mx, v);
            }
            int rep = blockIdx.x & (NREP - 1);
            atomicAdd(&meansum[rep * HH + f], sum);
            if (mx > -3.0e38f) atomicMax(&maxenc[rep * HH + f], encf(mx));
        }
        __syncthreads();
        if (t == 0 && slmax != ENC_NEG_INF) atomicMax(lmaxenc, slmax);
    }
}

// ---------- small finalize: fc, pass-MLP, v, global max M ----------
__global__ void k_fin1(const float* __restrict__ meansum, const unsigned* __restrict__ maxenc,
                       const unsigned* __restrict__ lmaxenc,
                       const float* __restrict__ val_w, const float* __restrict__ val_b,
                       const float* __restrict__ pe, const float* __restrict__ cl_w,
                       const float* __restrict__ cl_b, const float* __restrict__ pw1,
                       const float* __restrict__ pb1, const float* __restrict__ pw2,
                       const float* __restrict__ pb2, float* __restrict__ scal,
                       float* __restrict__ d_out) {
    __shared__ float xp[144];
    __shared__ float msum[HH];
    __shared__ float zp[HH];
    int t = threadIdx.x;
    if (t < HH) {
        float s = 0.f;
        unsigned mx = ENC_NEG_INF;
#pragma unroll
        for (int r = 0; r < NREP; ++r) {
            s += meansum[r * HH + t];
            unsigned e = maxenc[r * HH + t];
            if (e > mx) mx = e;
        }
        msum[t] = s;
        xp[t] = decf(mx);
    } else if (t < 144) {
        int c = t - HH;
        float s = cl_b[c];
        for (int k = 0; k < 30; ++k) s += pe[k] * cl_w[k * 16 + c];
        xp[t] = s;
    }
    __syncthreads();
    if (t < HH) {
        float s = pb1[t];
        for (int k = 0; k < 144; ++k) s += xp[k] * pw1[k * HH + t];
        zp[t] = fmaxf(s, 0.f);
    }
    __syncthreads();
    if (t < 64) {
        float s1 = zp[t] * pw2[t] + zp[t + 64] * pw2[t + 64];
        float s2 = msum[t] * val_w[t] + msum[t + 64] * val_w[t + 64];
#pragma unroll
        for (int off = 32; off > 0; off >>= 1) {
            s1 += __shfl_xor(s1, off, 64);
            s2 += __shfl_xor(s2, off, 64);
        }
        if (t == 0) {
            float xpass = s1 + pb2[0];
            float v = s2 * (1.0f / NN) + val_b[0];
            float M = fmaxf(decf(lmaxenc[0]), xpass);
            scal[0] = M;
            scal[1] = expf(xpass - M);
            d_out[NN + 1] = v;
        }
    }
}

// ---------- exp pass: unnormalized probs + sum ----------
__global__ __launch_bounds__(256) void k_exp(const float* __restrict__ logits,
                                             const int* __restrict__ ready,
                                             const float* __restrict__ scal,
                                             float* __restrict__ d_out,
                                             float* __restrict__ esum) {
    __shared__ float warr[4];
    int t = threadIdx.x;
    int i = blockIdx.x * 256 + t;
    float M = scal[0];
    float p = 0.f;
    if (i < NN) {
        if (ready[i] > 0) p = expf(logits[i] - M);
        d_out[i] = p;
    }
    float s = p;
#pragma unroll
    for (int off = 32; off > 0; off >>= 1) s += __shfl_xor(s, off, 64);
    if ((t & 63) == 0) warr[t >> 6] = s;
    __syncthreads();
    if (t == 0) atomicAdd(esum, warr[0] + warr[1] + warr[2] + warr[3]);
}

// ---------- normalize ----------
__global__ void k_scale(const float* __restrict__ esum, const float* __restrict__ scal,
                        float* __restrict__ d_out) {
    int i = blockIdx.x * blockDim.x + threadIdx.x;
    float inv = 1.0f / (esum[0] + scal[1]);
    if (i < NN) d_out[i] *= inv;
    else if (i == NN) d_out[NN] = scal[1] * inv;
}

extern "C" void kernel_launch(void* const* d_in, const int* in_sizes, int n_in,
                              void* d_out, int out_size, void* d_ws, size_t ws_size,
                              hipStream_t stream) {
    const float* x      = (const float*)d_in[0];
    const int*   edges  = (const int*)d_in[1];
    const float* eattr  = (const float*)d_in[2];
    const int*   ready  = (const int*)d_in[3];
    const float* pe     = (const float*)d_in[4];
    const float* gcn_w  = (const float*)d_in[5];
    const float* gcn_b  = (const float*)d_in[6];
    const float* mlp_w1 = (const float*)d_in[7];
    const float* mlp_b1 = (const float*)d_in[8];
    const float* mlp_w2 = (const float*)d_in[9];
    const float* mlp_b2 = (const float*)d_in[10];
    const float* val_w  = (const float*)d_in[11];
    const float* val_b  = (const float*)d_in[12];
    const float* cl_w   = (const float*)d_in[13];
    const float* cl_b   = (const float*)d_in[14];
    const float* pw1    = (const float*)d_in[15];
    const float* pb1    = (const float*)d_in[16];
    const float* pw2    = (const float*)d_in[17];
    const float* pb2    = (const float*)d_in[18];

    const int* rows = edges;
    const int* cols = edges + EE;

    // workspace carving (256B-aligned slices), ~92 MB
    char* P = (char*)d_ws;
    size_t off = 0;
    auto carve = [&](size_t bytes) {
        off = (off + 255) & ~(size_t)255;
        void* p = P + off;
        off += bytes;
        return p;
    };
    float* dis     = (float*)carve(NN * 4);
    float* logits  = (float*)carve(NN * 4);
    int*   count   = (int*)carve(NN * 4);
    int*   base    = (int*)carve((NN + 1) * 4);
    int*   bsum    = (int*)carve(256 * 4);
    ushort* bufB   = (ushort*)carve((size_t)NN * HH * 2);   // bf16 (gather out / gemm in)
    uchar* bufH    = (uchar*)carve((size_t)NN * HH);        // fp8 (gemm out / gather in)
    unsigned* csre = (unsigned*)carve((size_t)EE * 4);      // packed (col<<15|ea15)
    u64*   ebuck   = (u64*)carve((size_t)8 * CAP * 8);      // partition-major streams
    int*   fillptr = (int*)carve((size_t)8 * SS * PSZ * 4);
    float* meansum = (float*)carve(NREP * HH * 4);
    unsigned* maxenc = (unsigned*)carve(NREP * HH * 4);
    unsigned* lmaxenc = (unsigned*)carve(4);
    float* esum    = (float*)carve(4);
    float* scal    = (float*)carve(8);
    int*   gtail   = (int*)carve(8 * 4);
    ushort* wt     = (ushort*)carve(3 * HH * HH * 2);

    // alias (lifetime-disjoint): cnt (8*SS*PSZ int = 25.6MB, used k_cnt2..k_makeptr)
    // aliases bufB (25.6MB, first written by k_gather after fill2)
    int* cnt = (int*)bufB;

    float* out = (float*)d_out;

    const int nb = (NN + 255) / 256;
    const int gb = (NN + 63) / 64;
    const int ab = (NN + 15) / 16;          // gather: 16-lane group per node
    const int pb = 8 * SS;                  // cnt2/fill2 blocks

    k_init<<<(NREP * HH + 255) / 256, 256, 0, stream>>>(meansum, maxenc, lmaxenc, esum, gtail);
    k_prep<<<(3 * HH * HH + 255) / 256, 256, 0, stream>>>(gcn_w, gcn_w + HH * HH, mlp_w1, wt);

    // CSR build: bucket -> count -> scan -> fill (all coalesced, single-owner lines)
    k_bucket<<<NBB, 256, 0, stream>>>(rows, cols, eattr, gtail, ebuck);
    k_cnt2<<<pb, 256, 0, stream>>>(ebuck, gtail, cnt);
    k_rowsum<<<nb, 256, 0, stream>>>(cnt, count);
    k_scan1<<<NSCAN, 256, 0, stream>>>(count, base, bsum);
    k_scan2<<<1, 256, 0, stream>>>(bsum);
    k_scan3<<<nb, 256, 0, stream>>>(base, bsum);
    k_makeptr<<<nb, 256, 0, stream>>>(cnt, base, fillptr);
    k_fill2<<<pb, 256, 0, stream>>>(ebuck, gtail, fillptr, csre);
    k_degsum<<<nb, 256, 0, stream>>>(csre, base, dis);

    // layer 0
    k_mfma<0><<<gb, 256, 0, stream>>>(x, wt, bufH, dis, nullptr, nullptr, nullptr, nullptr,
                                      nullptr, nullptr, nullptr, nullptr, NN);
    k_gather<<<ab, 256, 0, stream>>>(bufH, csre, base, dis, gcn_b, bufB);

    // layer 1 (bf16 relu on staging)
    k_mfma<1><<<gb, 256, 0, stream>>>(bufB, wt + HH * HH, bufH, dis, nullptr, nullptr, nullptr,
                                      nullptr, nullptr, nullptr, nullptr, nullptr, NN);
    k_gather<<<ab, 256, 0, stream>>>(bufH, csre, base, dis, gcn_b + HH, bufB);

    // heads
    k_mfma<2><<<gb, 256, 0, stream>>>(bufB, wt + 2 * HH * HH, nullptr, nullptr, mlp_b1, mlp_w2,
                                      mlp_b2, ready, logits, meansum, maxenc, lmaxenc, NN);
    k_fin1<<<1, 256, 0, stream>>>(meansum, maxenc, lmaxenc, val_w, val_b, pe, cl_w, cl_b,
                                  pw1, pb1, pw2, pb2, scal, out);
    k_exp<<<nb, 256, 0, stream>>>(logits, ready, scal, out, esum);
    k_scale<<<(NN + 1 + 255) / 256, 256, 0, stream>>>(esum, scal, out);
}

// Round 4
// 337.562 us; speedup vs baseline: 1.3118x; 1.0710x over previous
//
#include <hip/hip_runtime.h>
#include <cstdint>

#define NN 100000
#define EE 1600000
#define HH 128
#define NREP 8
#define PSZ (NN / 8)                 // 12500 rows per partition
#define HPP (PSZ / 2)                // 6250 row-pairs per partition
#define SS 64                        // sub-slices per partition
#define CAP 300000                   // per-partition bucket capacity (entries)
#define NBB 500                      // bucket blocks
#define BCH 3200                     // edges per bucket block (500*3200 = EE)
#define SCAN_CHUNK 512
#define NSCAN ((NN + SCAN_CHUNK - 1) / SCAN_CHUNK)   // 196

typedef unsigned long long u64;
typedef unsigned short ushort;
typedef unsigned char uchar;
typedef __attribute__((ext_vector_type(8))) short bf16x8;
typedef __attribute__((ext_vector_type(4))) float f32x4;
typedef __attribute__((ext_vector_type(2))) float f32x2;

// ---------- bf16 helpers (RNE, finite values) ----------
__device__ __forceinline__ ushort f2bf(float x) {
    union { float f; unsigned u; } v; v.f = x;
    unsigned r = v.u + 0x7fffu + ((v.u >> 16) & 1u);
    return (ushort)(r >> 16);
}
__device__ __forceinline__ float bf2f(unsigned h16) {
    union { unsigned u; float f; } v; v.u = h16 << 16; return v.f;
}

// ---------- fp8 e4m3 helpers (HW cvt) ----------
__device__ __forceinline__ uchar f2fp8(float a) {
    return (uchar)(__builtin_amdgcn_cvt_pk_fp8_f32(a, a, 0, false) & 0xff);
}
__device__ __forceinline__ void unpack8_fp8(uint2 q, float* v) {
    f32x2 a = __builtin_amdgcn_cvt_pk_f32_fp8(q.x, false);
    f32x2 b = __builtin_amdgcn_cvt_pk_f32_fp8(q.x, true);
    f32x2 c = __builtin_amdgcn_cvt_pk_f32_fp8(q.y, false);
    f32x2 d = __builtin_amdgcn_cvt_pk_f32_fp8(q.y, true);
    v[0] = a[0]; v[1] = a[1]; v[2] = b[0]; v[3] = b[1];
    v[4] = c[0]; v[5] = c[1]; v[6] = d[0]; v[7] = d[1];
}

// ---------- monotone float<->uint encoding for atomicMax on floats ----------
__device__ __forceinline__ unsigned encf(float f) {
    int b = __float_as_int(f);
    return (b >= 0) ? ((unsigned)b | 0x80000000u) : ~(unsigned)b;
}
__device__ __forceinline__ float decf(unsigned u) {
    return (u & 0x80000000u) ? __int_as_float((int)(u & 0x7fffffffu))
                             : __int_as_float((int)(~u));
}
#define ENC_NEG_INF 0x007FFFFFu  // encf(-inf)

// ---------- setup: init accumulators + pre-transpose weights to bf16 Wt[n][k] ----------
__global__ void k_setup(float* __restrict__ meansum, unsigned* __restrict__ maxenc,
                        unsigned* __restrict__ lmaxenc, float* __restrict__ esum,
                        int* __restrict__ gtail,
                        const float* __restrict__ w0, const float* __restrict__ w1,
                        const float* __restrict__ w2, ushort* __restrict__ wt) {
    int idx = blockIdx.x * blockDim.x + threadIdx.x;
    if (idx < NREP * HH) { meansum[idx] = 0.f; maxenc[idx] = ENC_NEG_INF; }
    if (idx < 8) gtail[idx] = 0;
    if (idx == 0) { lmaxenc[0] = ENC_NEG_INF; esum[0] = 0.f; }
    if (idx < 3 * HH * HH) {
        int mat = idx >> 14;
        int e = idx & 16383;
        int n = e >> 7, k = e & 127;
        const float* src = (mat == 0) ? w0 : (mat == 1) ? w1 : w2;
        wt[idx] = f2bf(src[k * HH + n]);
    }
}

// ---------- bucket: split edges into 8 partition-major packed streams ----------
// entry: (rlocal << 32) | (col << 15) | q15
__global__ __launch_bounds__(256) void k_bucket(const int* __restrict__ rows,
                                                const int* __restrict__ cols,
                                                const float* __restrict__ ea,
                                                int* __restrict__ gtail,
                                                u64* __restrict__ ebuck) {
    __shared__ u64 buf[8][1024];   // 64 KB
    __shared__ int cnt8[8];
    __shared__ int rsv[8];
    int t = threadIdx.x;
    if (t < 8) cnt8[t] = 0;
    __syncthreads();
    int e0 = blockIdx.x * BCH;
    int e1 = e0 + BCH;
    for (int ebase = e0; ebase < e1; ebase += 1024) {
        int e = ebase + t * 4;
        if (e < e1) {
            int4 r4 = *(const int4*)(rows + e);
            int4 c4 = *(const int4*)(cols + e);
            float4 a4 = *(const float4*)(ea + e);
            int rr[4] = {r4.x, r4.y, r4.z, r4.w};
            int cc[4] = {c4.x, c4.y, c4.z, c4.w};
            float aa[4] = {a4.x, a4.y, a4.z, a4.w};
#pragma unroll
            for (int j = 0; j < 4; ++j) {
                int p = rr[j] / PSZ;
                int rl = rr[j] - p * PSZ;
                unsigned q = (unsigned)(aa[j] * 32767.0f + 0.5f);
                u64 en = ((u64)rl << 32) | (u64)(((unsigned)cc[j] << 15) | q);
                int idx = atomicAdd(&cnt8[p], 1);
                buf[p][idx] = en;
            }
        }
        __syncthreads();
        if (t < 8) rsv[t] = atomicAdd(&gtail[t], cnt8[t]);
        __syncthreads();
#pragma unroll
        for (int p = 0; p < 8; ++p) {
            int nn = cnt8[p], oo = rsv[p];
            u64* dst = ebuck + (size_t)p * CAP + oo;
            for (int j = t; j < nn; j += 256) dst[j] = buf[p][j];
        }
        __syncthreads();
        if (t < 8) cnt8[t] = 0;
        __syncthreads();
    }
}

// ---------- count: per-(partition,sub-slice) LDS u16x2 histogram, packed out ----------
__global__ __launch_bounds__(256) void k_cnt2(const u64* __restrict__ ebuck,
                                              const int* __restrict__ gtail,
                                              unsigned* __restrict__ cntp) {
    __shared__ unsigned h32[HPP];   // 25 KB
    int b = blockIdx.x;
    int s = b >> 3, p = b & 7;
    for (int j = threadIdx.x; j < HPP; j += 256) h32[j] = 0;
    __syncthreads();
    int pc = gtail[p];
    int len = (pc + SS - 1) / SS;
    int lo = s * len, hi = min(lo + len, pc);
    const u64* src = ebuck + (size_t)p * CAP;
    for (int i = lo + threadIdx.x; i < hi; i += 256) {
        int rl = (int)(src[i] >> 32);
        atomicAdd(&h32[rl >> 1], (rl & 1) ? 0x10000u : 1u);
    }
    __syncthreads();
    unsigned* dst = cntp + (size_t)(p * SS + s) * HPP;
    for (int j = threadIdx.x; j < HPP; j += 256) dst[j] = h32[j];
}

// ---------- fused rowsum+makeptr: count[r] totals + u16 exclusive deltas ----------
__global__ void k_rowdelta(const unsigned* __restrict__ cntp, int* __restrict__ count,
                           unsigned* __restrict__ deltap) {
    int rp = blockIdx.x * blockDim.x + threadIdx.x;   // row-pair index
    if (rp >= NN / 2) return;
    int p = rp / HPP, j = rp - p * HPP;
    unsigned s0 = 0, s1 = 0;
#pragma unroll 8
    for (int c = 0; c < SS; ++c) {
        size_t o = (size_t)(p * SS + c) * HPP + j;
        unsigned v = cntp[o];
        deltap[o] = s0 | (s1 << 16);   // exclusive prefix (fits u16: deg < 64k)
        s0 += v & 0xffffu;
        s1 += v >> 16;
    }
    int r0 = p * PSZ + 2 * j;
    *(int2*)(count + r0) = make_int2((int)s0, (int)s1);
}

// ---------- exclusive scan of count -> base ----------
__global__ void k_scan1(const int* __restrict__ cnt, int* __restrict__ out,
                        int* __restrict__ bsum) {
    int b = blockIdx.x, t = threadIdx.x;
    int i0 = b * SCAN_CHUNK + t * 2;
    int c0 = (i0 < NN) ? cnt[i0] : 0;
    int c1 = (i0 + 1 < NN) ? cnt[i0 + 1] : 0;
    int s = c0 + c1;
    int lane = t & 63, w = t >> 6;
    int v = s;
#pragma unroll
    for (int off = 1; off < 64; off <<= 1) {
        int u = __shfl_up(v, off, 64);
        if (lane >= off) v += u;
    }
    __shared__ int wsum[4];
    if (lane == 63) wsum[w] = v;
    __syncthreads();
    int wadd = 0;
    for (int j = 0; j < w; ++j) wadd += wsum[j];
    int incl = v + wadd;
    int excl = incl - s;
    if (i0 < NN) out[i0] = excl;
    if (i0 + 1 < NN) out[i0 + 1] = excl + c0;
    if (t == 255) bsum[b] = incl;
}

__global__ void k_scan2(int* __restrict__ bsum) {
    __shared__ int tmp[256];
    int t = threadIdx.x;
    int v = (t < NSCAN) ? bsum[t] : 0;
    tmp[t] = v;
    __syncthreads();
    for (int off = 1; off < 256; off <<= 1) {
        int u = (t >= off) ? tmp[t - off] : 0;
        __syncthreads();
        tmp[t] += u;
        __syncthreads();
    }
    if (t < NSCAN) bsum[t] = tmp[t] - v;  // exclusive
}

__global__ void k_scan3(int* __restrict__ out, const int* __restrict__ bsum) {
    int i = blockIdx.x * blockDim.x + threadIdx.x;
    if (i < NN) out[i] += bsum[i / SCAN_CHUNK];
    if (i == 0) out[NN] = EE;   // sentinel
}

// ---------- fill CSR from bucketed streams; nxt = base + u16 delta ----------
__global__ __launch_bounds__(256) void k_fill2(const u64* __restrict__ ebuck,
                                               const int* __restrict__ gtail,
                                               const unsigned* __restrict__ deltap,
                                               const int* __restrict__ base,
                                               unsigned* __restrict__ csre) {
    __shared__ int nxt[PSZ];   // 50 KB
    int b = blockIdx.x;
    int s = b >> 3, p = b & 7;
    const unsigned* dsrc = deltap + (size_t)(p * SS + s) * HPP;
    const int* bsrc = base + p * PSZ;
    for (int j = threadIdx.x; j < HPP; j += 256) {
        unsigned d = dsrc[j];
        int2 bb = *(const int2*)(bsrc + 2 * j);
        nxt[2 * j] = bb.x + (int)(d & 0xffffu);
        nxt[2 * j + 1] = bb.y + (int)(d >> 16);
    }
    __syncthreads();
    int pc = gtail[p];
    int len = (pc + SS - 1) / SS;
    int lo = s * len, hi = min(lo + len, pc);
    const u64* src = ebuck + (size_t)p * CAP;
    for (int i = lo + threadIdx.x; i < hi; i += 256) {
        u64 en = src[i];
        int rl = (int)(en >> 32);
        int slot = atomicAdd(&nxt[rl], 1);
        csre[slot] = (unsigned)(en & 0xffffffffu);
    }
}

// ---------- deg from csre segment sums -> dis ----------
__global__ void k_degsum(const unsigned* __restrict__ csre, const int* __restrict__ base,
                         float* __restrict__ dis) {
    int r = blockIdx.x * blockDim.x + threadIdx.x;
    if (r >= NN) return;
    int lo = base[r], hi = base[r + 1];
    float s = 0.f;
    for (int e = lo; e < hi; ++e) s += (float)(csre[e] & 0x7fffu);
    dis[r] = rsqrtf(1.0f + s * (1.0f / 32767.0f));
}

// ---------- gather: 16-lane group per node (4 nodes/wave); fp8 rows in, bf16 out ----------
// v3: 8 edge-slots per iteration (8 row-loads in flight per group) — the gather
// is L2/L3-latency-bound on random 128B rows; deeper MLP halves exposure count.
// Pad slots: clamped in-bounds load + zero weight.
__global__ __launch_bounds__(256) void k_gather(const uchar* __restrict__ hW,
                                                const unsigned* __restrict__ csre,
                                                const int* __restrict__ base,
                                                const float* __restrict__ dis,
                                                const float* __restrict__ bias,
                                                ushort* __restrict__ agg) {
    int node = blockIdx.x * 16 + (threadIdx.x >> 4);
    if (node >= NN) return;
    int l = threadIdx.x & 15;
    int f = l * 8;                     // byte offset within 128B row
    int lo = base[node], hi = base[node + 1];
    float disn = dis[node];
    float wk = disn * (1.0f / 32767.0f);
    float acc[8];
    {   // self-loop (all 16 lanes of the group)
        uint2 q = *(const uint2*)(hW + (size_t)node * HH + f);
        float v[8]; unpack8_fp8(q, v);
#pragma unroll
        for (int j = 0; j < 8; ++j) acc[j] = disn * v[j];
    }
    for (int eb = lo; eb < hi; eb += 8) {
        unsigned pp[8];
#pragma unroll
        for (int j = 0; j < 8; ++j)
            pp[j] = csre[min(eb + j, hi - 1)];
        uint2 qq[8];
#pragma unroll
        for (int j = 0; j < 8; ++j)
            qq[j] = *(const uint2*)(hW + (size_t)(pp[j] >> 15) * HH + f);
#pragma unroll
        for (int j = 0; j < 8; ++j) {
            float w = (eb + j < hi) ? (float)(pp[j] & 0x7fffu) * wk : 0.f;
            float v[8]; unpack8_fp8(qq[j], v);
#pragma unroll
            for (int k = 0; k < 8; ++k) acc[k] += w * v[k];
        }
    }
    float4 b0 = *(const float4*)(bias + f);
    float4 b1 = *(const float4*)(bias + f + 4);
    ushort o[8];
    o[0] = f2bf(acc[0] + b0.x); o[1] = f2bf(acc[1] + b0.y);
    o[2] = f2bf(acc[2] + b0.z); o[3] = f2bf(acc[3] + b0.w);
    o[4] = f2bf(acc[4] + b1.x); o[5] = f2bf(acc[5] + b1.y);
    o[6] = f2bf(acc[6] + b1.z); o[7] = f2bf(acc[7] + b1.w);
    *(uint4*)(agg + (size_t)node * HH + f) = *(uint4*)o;
}

// ---------- MFMA GEMM: 64x128 tile, K=128, bf16 inputs, fp32 acc ----------
// B (Wt) staged once per block into LDS (swizzled).
// MODE 0: A fp32 (x), no relu    -> C_fp8 = fp8(dis*(A@W))
// MODE 1: A bf16, relu           -> C_fp8 = fp8(dis*(relu(A)@W))
// MODE 2: A bf16, relu; heads: logits + mean/masked-max
template <int MODE>
__global__ __launch_bounds__(256) void k_mfma(const void* __restrict__ Ain,
                                              const ushort* __restrict__ Wt,
                                              uchar* __restrict__ C,
                                              const float* __restrict__ dis,
                                              const float* __restrict__ b1,
                                              const float* __restrict__ w2v,
                                              const float* __restrict__ b2,
                                              const int* __restrict__ ready,
                                              float* __restrict__ logits,
                                              float* __restrict__ meansum,
                                              unsigned* __restrict__ maxenc,
                                              unsigned* __restrict__ lmaxenc, int n) {
    __shared__ ushort As[64 * HH];    // 16 KB, swizzled: elem(m,k) at m*128 + ((k>>3)^(m&15))*8 + (k&7)
    __shared__ ushort Ws[128 * HH];   // 32 KB, same swizzle
    __shared__ int rdy[64];
    __shared__ unsigned slmax;
    const int t = threadIdx.x;
    const int rb = blockIdx.x * 64;
    if (MODE == 2) {
        if (t < 64) rdy[t] = (rb + t < n) ? ready[rb + t] : 0;
        if (t == 0) slmax = ENC_NEG_INF;
    }
    // stage Wt tile (bf16, swizzled) — 128 rows x 16 chunks, 8 chunks/thread
#pragma unroll
    for (int i = 0; i < 8; ++i) {
        int nr = i * 16 + (t >> 4);
        int gc = t & 15;
        uint4 q = *(const uint4*)(Wt + (size_t)nr * HH + gc * 8);
        *(uint4*)(Ws + nr * HH + ((gc ^ (nr & 15)) * 8)) = q;
    }
    // stage A tile (bf16, swizzled)
#pragma unroll
    for (int i = 0; i < 4; ++i) {
        int m = i * 16 + (t >> 4);
        int k = (t & 15) * 8;
        ushort pk[8];
        if (MODE == 0) {
            const float* Af = (const float*)Ain;
            float4 v0 = make_float4(0.f, 0.f, 0.f, 0.f), v1 = v0;
            if (rb + m < n) {
                const float* src = Af + (size_t)(rb + m) * HH + k;
                v0 = *(const float4*)src;
                v1 = *(const float4*)(src + 4);
            }
            pk[0] = f2bf(v0.x); pk[1] = f2bf(v0.y); pk[2] = f2bf(v0.z); pk[3] = f2bf(v0.w);
            pk[4] = f2bf(v1.x); pk[5] = f2bf(v1.y); pk[6] = f2bf(v1.z); pk[7] = f2bf(v1.w);
        } else {
            const ushort* Au = (const ushort*)Ain;
            uint4 q = make_uint4(0, 0, 0, 0);
            if (rb + m < n) q = *(const uint4*)(Au + (size_t)(rb + m) * HH + k);
            *(uint4*)pk = q;
#pragma unroll
            for (int j = 0; j < 8; ++j) pk[j] = (pk[j] & 0x8000) ? (ushort)0 : pk[j];  // bf16 relu
        }
        int gsw = (t & 15) ^ (m & 15);
        *(uint4*)(As + m * HH + gsw * 8) = *(uint4*)pk;
    }
    __syncthreads();

    const int wave = t >> 6, lane = t & 63;
    const int cl = lane & 15;       // column-within-tile / A row
    const int kq = lane >> 4;       // k quad
    const int m0 = wave * 16;

    f32x4 acc[8];
#pragma unroll
    for (int c = 0; c < 8; ++c) acc[c] = (f32x4){0.f, 0.f, 0.f, 0.f};

    const int am = m0 + cl;
#pragma unroll
    for (int kk = 0; kk < 4; ++kk) {
        int g = kk * 4 + kq;
        bf16x8 a = *(const bf16x8*)(As + am * HH + ((g ^ cl) * 8));
#pragma unroll
        for (int c = 0; c < 8; ++c) {
            // B row nn = c*16+cl (nn&15 == cl), chunk g → swizzled slot g^cl
            bf16x8 b = *(const bf16x8*)(Ws + (c * 16 + cl) * HH + ((g ^ cl) * 8));
            acc[c] = __builtin_amdgcn_mfma_f32_16x16x32_bf16(a, b, acc[c], 0, 0, 0);
        }
    }

    if (MODE < 2) {
        // store C fp8 pre-scaled by dis[row]: D row = m0 + kq*4 + r, col = c*16 + cl
#pragma unroll
        for (int r = 0; r < 4; ++r) {
            int row = rb + m0 + kq * 4 + r;
            if (row < n) {
                float dsc = dis[row];
#pragma unroll
                for (int c = 0; c < 8; ++c)
                    C[(size_t)row * HH + c * 16 + cl] = f2fp8(acc[c][r] * dsc);
            }
        }
    } else {
        // heads epilogue
        float b1c[8], w2c[8];
#pragma unroll
        for (int c = 0; c < 8; ++c) { b1c[c] = b1[c * 16 + cl]; w2c[c] = w2v[c * 16 + cl]; }
        const float b2s = b2[0];
        unsigned mylmax = ENC_NEG_INF;
#pragma unroll
        for (int r = 0; r < 4; ++r) {
            float s = 0.f;
#pragma unroll
            for (int c = 0; c < 8; ++c)
                s += fmaxf(acc[c][r] + b1c[c], 0.f) * w2c[c];
            s += __shfl_xor(s, 1, 64);
            s += __shfl_xor(s, 2, 64);
            s += __shfl_xor(s, 4, 64);
            s += __shfl_xor(s, 8, 64);
            if (cl == 0) {
                int rloc = m0 + kq * 4 + r;
                int row = rb + rloc;
                if (row < n) {
                    float lg = s + b2s;
                    logits[row] = lg;
                    if (rdy[rloc] > 0) {
                        unsigned e = encf(lg);
                        if (e > mylmax) mylmax = e;
                    }
                }
            }
        }
        if (cl == 0 && mylmax != ENC_NEG_INF) atomicMax(&slmax, mylmax);

        // mean / masked-max of h = relu(A) (bf16 tile), per feature
        int lim = min(64, n - rb);
        if (t < HH) {
            int f = t, gf = f >> 3, fo = f & 7;
            float sum = 0.f, mx = -3.4e38f;
            for (int m = 0; m < lim; ++m) {
                float v = bf2f(As[m * HH + ((gf ^ (m & 15)) * 8) + fo]);
                sum += v;
                if (rdy[m] > 0) mx = fmaxf(mx, v);
            }
            int rep = blockIdx.x & (NREP - 1);
            atomicAdd(&meansum[rep * HH + f], sum);
            if (mx > -3.0e38f) atomicMax(&maxenc[rep * HH + f], encf(mx));
        }
        __syncthreads();
        if (t == 0 && slmax != ENC_NEG_INF) atomicMax(lmaxenc, slmax);
    }
}

// ---------- small finalize: fc, pass-MLP, v, global max M ----------
__global__ void k_fin1(const float* __restrict__ meansum, const unsigned* __restrict__ maxenc,
                       const unsigned* __restrict__ lmaxenc,
                       const float* __restrict__ val_w, const float* __restrict__ val_b,
                       const float* __restrict__ pe, const float* __restrict__ cl_w,
                       const float* __restrict__ cl_b, const float* __restrict__ pw1,
                       const float* __restrict__ pb1, const float* __restrict__ pw2,
                       const float* __restrict__ pb2, float* __restrict__ scal,
                       float* __restrict__ d_out) {
    __shared__ float xp[144];
    __shared__ float msum[HH];
    __shared__ float zp[HH];
    int t = threadIdx.x;
    if (t < HH) {
        float s = 0.f;
        unsigned mx = ENC_NEG_INF;
#pragma unroll
        for (int r = 0; r < NREP; ++r) {
            s += meansum[r * HH + t];
            unsigned e = maxenc[r * HH + t];
            if (e > mx) mx = e;
        }
        msum[t] = s;
        xp[t] = decf(mx);
    } else if (t < 144) {
        int c = t - HH;
        float s = cl_b[c];
        for (int k = 0; k < 30; ++k) s += pe[k] * cl_w[k * 16 + c];
        xp[t] = s;
    }
    __syncthreads();
    if (t < HH) {
        float s = pb1[t];
        for (int k = 0; k < 144; ++k) s += xp[k] * pw1[k * HH + t];
        zp[t] = fmaxf(s, 0.f);
    }
    __syncthreads();
    if (t < 64) {
        float s1 = zp[t] * pw2[t] + zp[t + 64] * pw2[t + 64];
        float s2 = msum[t] * val_w[t] + msum[t + 64] * val_w[t + 64];
#pragma unroll
        for (int off = 32; off > 0; off >>= 1) {
            s1 += __shfl_xor(s1, off, 64);
            s2 += __shfl_xor(s2, off, 64);
        }
        if (t == 0) {
            float xpass = s1 + pb2[0];
            float v = s2 * (1.0f / NN) + val_b[0];
            float M = fmaxf(decf(lmaxenc[0]), xpass);
            scal[0] = M;
            scal[1] = expf(xpass - M);
            d_out[NN + 1] = v;
        }
    }
}

// ---------- exp pass: unnormalized probs + sum ----------
__global__ __launch_bounds__(256) void k_exp(const float* __restrict__ logits,
                                             const int* __restrict__ ready,
                                             const float* __restrict__ scal,
                                             float* __restrict__ d_out,
                                             float* __restrict__ esum) {
    __shared__ float warr[4];
    int t = threadIdx.x;
    int i = blockIdx.x * 256 + t;
    float M = scal[0];
    float p = 0.f;
    if (i < NN) {
        if (ready[i] > 0) p = expf(logits[i] - M);
        d_out[i] = p;
    }
    float s = p;
#pragma unroll
    for (int off = 32; off > 0; off >>= 1) s += __shfl_xor(s, off, 64);
    if ((t & 63) == 0) warr[t >> 6] = s;
    __syncthreads();
    if (t == 0) atomicAdd(esum, warr[0] + warr[1] + warr[2] + warr[3]);
}

// ---------- normalize ----------
__global__ void k_scale(const float* __restrict__ esum, const float* __restrict__ scal,
                        float* __restrict__ d_out) {
    int i = blockIdx.x * blockDim.x + threadIdx.x;
    float inv = 1.0f / (esum[0] + scal[1]);
    if (i < NN) d_out[i] *= inv;
    else if (i == NN) d_out[NN] = scal[1] * inv;
}

extern "C" void kernel_launch(void* const* d_in, const int* in_sizes, int n_in,
                              void* d_out, int out_size, void* d_ws, size_t ws_size,
                              hipStream_t stream) {
    const float* x      = (const float*)d_in[0];
    const int*   edges  = (const int*)d_in[1];
    const float* eattr  = (const float*)d_in[2];
    const int*   ready  = (const int*)d_in[3];
    const float* pe     = (const float*)d_in[4];
    const float* gcn_w  = (const float*)d_in[5];
    const float* gcn_b  = (const float*)d_in[6];
    const float* mlp_w1 = (const float*)d_in[7];
    const float* mlp_b1 = (const float*)d_in[8];
    const float* mlp_w2 = (const float*)d_in[9];
    const float* mlp_b2 = (const float*)d_in[10];
    const float* val_w  = (const float*)d_in[11];
    const float* val_b  = (const float*)d_in[12];
    const float* cl_w   = (const float*)d_in[13];
    const float* cl_b   = (const float*)d_in[14];
    const float* pw1    = (const float*)d_in[15];
    const float* pb1    = (const float*)d_in[16];
    const float* pw2    = (const float*)d_in[17];
    const float* pb2    = (const float*)d_in[18];

    const int* rows = edges;
    const int* cols = edges + EE;

    // workspace carving (256B-aligned slices)
    char* P = (char*)d_ws;
    size_t off = 0;
    auto carve = [&](size_t bytes) {
        off = (off + 255) & ~(size_t)255;
        void* p = P + off;
        off += bytes;
        return p;
    };
    float* dis     = (float*)carve(NN * 4);
    float* logits  = (float*)carve(NN * 4);
    int*   count   = (int*)carve(NN * 4);
    int*   base    = (int*)carve((NN + 1) * 4);
    int*   bsum    = (int*)carve(256 * 4);
    ushort* bufB   = (ushort*)carve((size_t)NN * HH * 2);   // bf16 (gather out / gemm in)
    uchar* bufH    = (uchar*)carve((size_t)NN * HH);        // fp8 (gemm out / gather in)
    unsigned* csre = (unsigned*)carve((size_t)EE * 4);      // packed (col<<15|ea15)
    u64*   ebuck   = (u64*)carve((size_t)8 * CAP * 8);      // partition-major streams
    float* meansum = (float*)carve(NREP * HH * 4);
    unsigned* maxenc = (unsigned*)carve(NREP * HH * 4);
    unsigned* lmaxenc = (unsigned*)carve(4);
    float* esum    = (float*)carve(4);
    float* scal    = (float*)carve(8);
    int*   gtail   = (int*)carve(8 * 4);
    ushort* wt     = (ushort*)carve(3 * HH * HH * 2);

    // aliases (lifetime-disjoint with bufB, which k_gather first writes after fill2):
    // cntp  = packed u16x2 counts   (8*SS*HPP u32 = 12.8 MB)
    // deltap= packed u16x2 deltas   (8*SS*HPP u32 = 12.8 MB)
    unsigned* cntp   = (unsigned*)bufB;
    unsigned* deltap = (unsigned*)bufB + (size_t)8 * SS * HPP;

    float* out = (float*)d_out;

    const int nb = (NN + 255) / 256;
    const int gb = (NN + 63) / 64;
    const int ab = (NN + 15) / 16;          // gather: 16-lane group per node
    const int pb = 8 * SS;                  // cnt2/fill2 blocks

    k_setup<<<(3 * HH * HH + 255) / 256, 256, 0, stream>>>(meansum, maxenc, lmaxenc, esum,
                                                           gtail, gcn_w, gcn_w + HH * HH,
                                                           mlp_w1, wt);

    // CSR build: bucket -> count -> rowdelta -> scan -> fill
    k_bucket<<<NBB, 256, 0, stream>>>(rows, cols, eattr, gtail, ebuck);
    k_cnt2<<<pb, 256, 0, stream>>>(ebuck, gtail, cntp);
    k_rowdelta<<<(NN / 2 + 255) / 256, 256, 0, stream>>>(cntp, count, deltap);
    k_scan1<<<NSCAN, 256, 0, stream>>>(count, base, bsum);
    k_scan2<<<1, 256, 0, stream>>>(bsum);
    k_scan3<<<nb, 256, 0, stream>>>(base, bsum);
    k_fill2<<<pb, 256, 0, stream>>>(ebuck, gtail, deltap, base, csre);
    k_degsum<<<nb, 256, 0, stream>>>(csre, base, dis);

    // layer 0
    k_mfma<0><<<gb, 256, 0, stream>>>(x, wt, bufH, dis, nullptr, nullptr, nullptr, nullptr,
                                      nullptr, nullptr, nullptr, nullptr, NN);
    k_gather<<<ab, 256, 0, stream>>>(bufH, csre, base, dis, gcn_b, bufB);

    // layer 1 (bf16 relu on staging)
    k_mfma<1><<<gb, 256, 0, stream>>>(bufB, wt + HH * HH, bufH, dis, nullptr, nullptr, nullptr,
                                      nullptr, nullptr, nullptr, nullptr, nullptr, NN);
    k_gather<<<ab, 256, 0, stream>>>(bufH, csre, base, dis, gcn_b + HH, bufB);

    // heads
    k_mfma<2><<<gb, 256, 0, stream>>>(bufB, wt + 2 * HH * HH, nullptr, nullptr, mlp_b1, mlp_w2,
                                      mlp_b2, ready, logits, meansum, maxenc, lmaxenc, NN);
    k_fin1<<<1, 256, 0, stream>>>(meansum, maxenc, lmaxenc, val_w, val_b, pe, cl_w, cl_b,
                                  pw1, pb1, pw2, pb2, scal, out);
    k_exp<<<nb, 256, 0, stream>>>(logits, ready, scal, out, esum);
    k_scale<<<(NN + 1 + 255) / 256, 256, 0, stream>>>(esum, scal, out);
}